// Round 2
// baseline (219.052 us; speedup 1.0000x reference)
//
#include <hip/hip_runtime.h>
#include <math.h>

// Problem constants (fixed by reference setup_inputs)
#define L0   4448   // flux length
#define L1P  278    // after conv1(stride4,pad7)->1112 then maxpool4
#define L2   139    // after conv2(stride2,pad3) on 278
#define NQ   8
#define NL   3
#define SD   256

// LDS element/word map (float S[5620] = 22480 B)  [R14: Wb aliased into fxb]
//  fxb  bf16[4496]      el 0..4495      flux[x] at el x+8; el 0..7 & 4456..4495 zero
//  h1T  bf16[286][20]   el 4496..10215  row = pooled pos + 4; rows 0..3, 282..285 zero
//                       (rows 0..3 zero also serve as fxb overread pad, el<=4507)
//  Wc1  bf16[16][32]    el 10216..10727 conv1 weights (sign-flipped), K'=1..15 taps
//  featU f32[256]       words 5364..5619 (pool sums; s_U after proj1 — R4 invariant)
//  Wb   bf16[32][136]   el 0..4351      conv2 weights — written AFTER stage 1 into the
//                       dead fxb region (prefetched to regs in stage 0); read in stage 2.
// Aliases into dead fxb/Wb after stage2 (words 0..2247):
//  s_hidden w0..63, s_red w64..95, s_q w96..103,
//  amp re buffer w256..511, amp im / perm scratch w512..767
#define H1T_EL 4496
#define WB_EL  0
#define WC1_EL 10216
#define FTW    5364

typedef __attribute__((ext_vector_type(4))) short short4v;
typedef __attribute__((ext_vector_type(8))) short short8;
typedef __attribute__((ext_vector_type(4))) float f32x4;
union FragU { short8 v; short4v h[2]; };

__device__ __forceinline__ short f2bf(float x) {   // fp32 -> bf16 (RNE)
    unsigned u = __float_as_uint(x);
    u += 0x7FFFu + ((u >> 16) & 1u);
    return (short)(u >> 16);
}

__device__ __forceinline__ short8 pack8(float4 a, float4 b) {
    short8 v;
    v[0] = f2bf(a.x); v[1] = f2bf(a.y); v[2] = f2bf(a.z); v[3] = f2bf(a.w);
    v[4] = f2bf(b.x); v[5] = f2bf(b.y); v[6] = f2bf(b.z); v[7] = f2bf(b.w);
    return v;
}

// CNOT-ring permutation (one layer of 8 CNOTs composed). Linear over GF(2).
constexpr int permsrc_c(int x) {
    for (int q = 7; q >= 0; --q) {
        int cb = 7 - q, tb = 7 - ((q + 1) & 7);
        x ^= ((x >> cb) & 1) << tb;
    }
    return x;
}
constexpr int P40 = permsrc_c(0x40);
constexpr int P80 = permsrc_c(0x80);
constexpr int PC0 = permsrc_c(0xC0);

__device__ __forceinline__ int permsrc(int x) {
    #pragma unroll
    for (int q = 7; q >= 0; --q) {
        int cb = 7 - q, tb = 7 - ((q + 1) & 7);
        x ^= ((x >> cb) & 1) << tb;
    }
    return x;
}

__global__ __launch_bounds__(256, 6)
void aec_fused_kernel(const float* __restrict__ flux,
                      const float* __restrict__ scalars,
                      const float* __restrict__ conv1_w,
                      const float* __restrict__ bn1_g, const float* __restrict__ bn1_b,
                      const float* __restrict__ conv2_w,
                      const float* __restrict__ bn2_g, const float* __restrict__ bn2_b,
                      const float* __restrict__ proj_w1, const float* __restrict__ proj_b1,
                      const float* __restrict__ proj_w2, const float* __restrict__ proj_b2,
                      const float* __restrict__ qw,
                      const float* __restrict__ head_w1, const float* __restrict__ head_b1,
                      const float* __restrict__ head_bn_g, const float* __restrict__ head_bn_b,
                      const float* __restrict__ head_w2, const float* __restrict__ head_b2,
                      float* __restrict__ out)
{
    const int b   = blockIdx.x;
    const int tid = threadIdx.x;

    __shared__ __align__(16) float S[5620];

    float* s_hidden = S;
    float* s_red    = S + 64;
    float* s_q      = S + 96;
    float* featU    = S + FTW;
    float* s_U      = S + FTW;      // gates overwrite featU AFTER proj1 (R4 invariant)

    const float BN_RSQ = 0.9999950000374997f;     // 1/sqrt(1+1e-5)

    // ---------------- stage 0: zeros + weight staging + flux staging ----------
    featU[tid] = 0.0f;
    if (tid < 4)                    S[tid] = 0.0f;          // fxb el 0..7
    else if (tid < 64)              S[2224 + tid] = 0.0f;   // fxb tail + h1T rows 0..3
    else if (tid < 104)             S[5004 + tid] = 0.0f;   // h1T rows 282..285
    {
        // Wc1[oc][k'] bf16: k'=0 zero, k'=1..15 = sgn*conv1_w[oc][k'-1], 16..31 zero.
        // Sign flip (exact) makes every effective bn1 scale >= 0 so maxpool can
        // run BEFORE the affine (monotone composition).
        const int oc = tid >> 4;
        const int q  = tid & 15;
        const float sgn = (bn1_g[oc] >= 0.0f) ? 1.0f : -1.0f;
        const int k0 = 2 * q, k1 = 2 * q + 1;
        const short e0 = (k0 >= 1 && k0 <= 15) ? f2bf(sgn * conv1_w[oc * 15 + k0 - 1]) : (short)0;
        const short e1 = (k1 <= 15)            ? f2bf(sgn * conv1_w[oc * 15 + k1 - 1]) : (short)0;
        const unsigned pk = (unsigned short)e0 | ((unsigned)(unsigned short)e1 << 16);
        *(unsigned*)((short*)S + WC1_EL + oc * 32 + 2 * q) = pk;
    }
    // Wb prefetch to REGISTERS only (Wb LDS region still holds live fxb data;
    // the ds_write happens after stage 1). Loads overlap flux HBM latency.
    short8 wbp0, wbp1;
    {
        const int oc = tid >> 3;
        const int k  = tid & 7;
        #pragma unroll
        for (int e = 0; e < 8; ++e) {
            wbp0[e] = (k < 7) ? f2bf(conv2_w[oc * 112 + e * 7 + k])       : (short)0;
            wbp1[e] = (k < 7) ? f2bf(conv2_w[oc * 112 + (8 + e) * 7 + k]) : (short)0;
        }
    }
    {
        // flux -> bf16 LDS (el x+8): 8 els per iteration, b128 stores.
        const float4* fg = (const float4*)(flux + (size_t)b * L0);
        short* fx = (short*)S;
        for (int t = tid; t < 556; t += 256) {
            float4 v0 = fg[2 * t], v1 = fg[2 * t + 1];
            *(short8*)(fx + 8 + 8 * t) = pack8(v0, v1);
        }
    }
    __syncthreads();

    // ---------------- stage 1: conv1 as MFMA (transposed D) + pool + bn --------
    // (R9-verified) D[j][oc] = X^T[16 j][32 k'] x Wc1^T[32][16 oc].
    {
        const int lane = tid & 63;
        const int wid  = tid >> 6;
        const int col  = lane & 15;
        const int quad = lane >> 4;
        const short* fx = (const short*)S;
        const short8 wfrag = *(const short8*)((const short*)S + WC1_EL + col * 32 + quad * 8);
        const float gsc = fabsf(bn1_g[col]) * BN_RSQ;
        const float gbt = bn1_b[col];

        for (int nt = wid; nt < 70; nt += 4) {
            const int jl = nt * 16 + col;          // A's m-row = conv position
            FragU xu;
            xu.h[0] = *(const short4v*)(fx + 4 * jl + quad * 8);
            xu.h[1] = *(const short4v*)(fx + 4 * jl + quad * 8 + 4);
            f32x4 acc = {0.f, 0.f, 0.f, 0.f};
            acc = __builtin_amdgcn_mfma_f32_16x16x32_bf16(xu.v, wfrag, acc, 0, 0, 0);
            const float m = fmaxf(fmaxf(acc[0], acc[1]), fmaxf(acc[2], acc[3]));
            const int p = nt * 4 + quad;           // pooled position
            if (p < L1P) {
                *((short*)S + H1T_EL + (4 + p) * 20 + col) =
                    f2bf(fmaxf(m * gsc + gbt, 0.0f));
            }
        }
    }
    __syncthreads();   // h1T complete; fxb now dead

    // Wb[oc][K'=k*16+ic] bf16, row stride 136 (k==7 row zero) -> dead fxb region.
    {
        const int oc = tid >> 3;
        const int k  = tid & 7;
        short8* dst = (short8*)((char*)S + (WB_EL + oc * 136 + k * 16) * 2);
        dst[0] = wbp0; dst[1] = wbp1;
    }
    __syncthreads();   // Wb ready; featU still pure pool sums

    // ---------------- stage 2: conv2 as MFMA (transposed D) + bn/relu + pool ----
    // (R9/R12-verified) D[j][oc] = X^T[144 j][128] x Wb^T[128][32 oc];
    // weight fragments hoisted (nt-invariant).
    {
        const int lane = tid & 63;
        const int wid  = tid >> 6;
        const int col  = lane & 15;
        const int quad = lane >> 4;
        const short* h1s = (const short*)S + H1T_EL;
        const char*  wbc = (const char*)((const short*)S + WB_EL);
        const float sc0 = bn2_g[col] * BN_RSQ,      bt0 = bn2_b[col];
        const float sc1 = bn2_g[col + 16] * BN_RSQ, bt1 = bn2_b[col + 16];

        short8 wa0[4], wa1[4];
        #pragma unroll
        for (int kb = 0; kb < 4; ++kb) {
            wa0[kb] = *(const short8*)(wbc + (col * 136        + kb*32 + quad*8) * 2);
            wa1[kb] = *(const short8*)(wbc + ((16 + col) * 136 + kb*32 + quad*8) * 2);
        }

        for (int nt = wid; nt < 9; nt += 4) {
            const int n0 = nt * 16;
            f32x4 acc0 = {0.f,0.f,0.f,0.f}, acc1 = {0.f,0.f,0.f,0.f};
            #pragma unroll
            for (int kb = 0; kb < 4; ++kb) {
                const int k   = 2 * kb + (quad >> 1);
                const int ic0 = (quad & 1) * 8;
                const int row = 2 * (n0 + col) + 1 + k;
                FragU bu;
                bu.h[0] = *(const short4v*)(h1s + row * 20 + ic0);
                bu.h[1] = *(const short4v*)(h1s + row * 20 + ic0 + 4);
                acc0 = __builtin_amdgcn_mfma_f32_16x16x32_bf16(bu.v, wa0[kb], acc0, 0, 0, 0);
                acc1 = __builtin_amdgcn_mfma_f32_16x16x32_bf16(bu.v, wa1[kb], acc1, 0, 0, 0);
            }
            const int   bA  = (8 * n0) / 139;
            const int   sB  = (139 * (bA + 1)) >> 3;      // j<=sB -> bA; j>=sB -> bA+1
            const float rcA = (bA == 2 || bA == 5) ? (1.0f/19.0f) : (1.0f/18.0f);
            const float rcB = (bA == 1 || bA == 4) ? (1.0f/19.0f) : (1.0f/18.0f);
            float va0 = 0.f, vb0 = 0.f, va1 = 0.f, vb1 = 0.f;
            #pragma unroll
            for (int r = 0; r < 4; ++r) {
                const int j = n0 + quad * 4 + r;
                float v0 = fmaxf(acc0[r] * sc0 + bt0, 0.0f);
                float v1 = fmaxf(acc1[r] * sc1 + bt1, 0.0f);
                if (j > 138) { v0 = 0.0f; v1 = 0.0f; }
                if (j <= sB) { va0 += v0; va1 += v1; }
                if (j >= sB) { vb0 += v0; vb1 += v1; }
            }
            va0 += __shfl_xor(va0, 16, 64); va0 += __shfl_xor(va0, 32, 64);
            va1 += __shfl_xor(va1, 16, 64); va1 += __shfl_xor(va1, 32, 64);
            vb0 += __shfl_xor(vb0, 16, 64); vb0 += __shfl_xor(vb0, 32, 64);
            vb1 += __shfl_xor(vb1, 16, 64); vb1 += __shfl_xor(vb1, 32, 64);
            if (quad == 0) {
                atomicAdd(&featU[col * 8 + bA],        va0 * rcA);
                atomicAdd(&featU[(col + 16) * 8 + bA], va1 * rcA);
                if (bA < 7) {
                    atomicAdd(&featU[col * 8 + bA + 1],        vb0 * rcB);
                    atomicAdd(&featU[(col + 16) * 8 + bA + 1], vb1 * rcB);
                }
            }
        }
    }
    __syncthreads();

    // ---------------- proj1 (256 -> 64), relu ----------------
    {
        const int o = tid >> 2, s = tid & 3;
        const float4* wg = (const float4*)(proj_w1 + 64 * tid);   // == o*256 + s*64
        const float4* xf = (const float4*)(featU + 64 * s);
        float acc = 0.0f;
        #pragma unroll
        for (int t = 0; t < 16; ++t) {
            float4 w4 = wg[t], x4 = xf[t];
            acc += w4.x * x4.x + w4.y * x4.y + w4.z * x4.z + w4.w * x4.w;
        }
        acc += __shfl_down(acc, 2, 64);
        acc += __shfl_down(acc, 1, 64);
        if (s == 0) s_hidden[o] = fmaxf(acc + proj_b1[o], 0.0f);
    }
    __syncthreads();

    // gate matrices into featU (feat consumed — only safe place, R4 invariant);
    // published by the __syncthreads() inside the normalize sequence below.
    if (tid < NL * NQ) {
        float phi = qw[tid * 3 + 0], th = qw[tid * 3 + 1], om = qw[tid * 3 + 2];
        float ch = cosf(0.5f * th), sh = sinf(0.5f * th);
        float a  = 0.5f * (phi + om), bb = 0.5f * (phi - om);
        float ca = cosf(a), sa = sinf(a), cb = cosf(bb), sb = sinf(bb);
        float* U = &s_U[tid * 8];
        U[0] =  ca * ch; U[1] = -sa * ch;   // U00
        U[2] = -cb * sh; U[3] = -sb * sh;   // U01
        U[4] =  cb * sh; U[5] = -sb * sh;   // U10
        U[6] =  ca * ch; U[7] =  sa * ch;   // U11
    }

    // ---------------- proj2 (64 -> 256) + L2 normalize ----------------
    float re;
    {
        const float4* wg = (const float4*)(proj_w2 + 64 * tid);
        const float4* hf = (const float4*)s_hidden;
        float acc = proj_b2[tid];
        #pragma unroll
        for (int t = 0; t < 16; ++t) {
            float4 w4 = wg[t], x4 = hf[t];
            acc += w4.x * x4.x + w4.y * x4.y + w4.z * x4.z + w4.w * x4.w;
        }
        float ss = acc * acc;
        #pragma unroll
        for (int off = 32; off >= 1; off >>= 1) ss += __shfl_xor(ss, off, 64);
        if ((tid & 63) == 0) s_red[tid >> 6] = ss;
        __syncthreads();                           // also publishes s_U
        float sst = s_red[0] + s_red[1] + s_red[2] + s_red[3];
        float n   = sqrtf(sst);
        float inv = 1.0f / fmaxf(n, 1e-12f);
        float xi  = acc * inv;
        if (n * inv < 1e-8f) xi = 0.0625f;        // uniform 1/sqrt(256)
        re = xi;                                   // initial state is real (im = 0)
    }

    // ---------------- publish amplitudes; single barrier; wave-0 tail ----------
    float* areb = S + 256;     // 256-amp re buffer / perm scratch
    float* aimb = S + 512;     // 256-amp im buffer / perm scratch
    areb[tid] = re;
    __syncthreads();           // last barrier: amps + s_U visible to wave 0

    // R13: the whole circuit+Walsh+head runs in wave 0 with 4 amps/lane
    // (amp index bits 6,7 = register index). q=0,1 gates are register-local;
    // q=2..7 are lane shuffles; the CNOT permutation and the tiny s_q handoff
    // use intra-wave LDS (program-ordered, no barrier). Waves 1-3 exit early.
    if (tid < 64) {
        const int lane = tid;
        const int sPl  = permsrc(lane);
        float xr[4], xi4[4];
        #pragma unroll
        for (int r = 0; r < 4; ++r) { xr[r] = areb[64 * r + lane]; xi4[r] = 0.0f; }

        #pragma unroll
        for (int l = 0; l < NL; ++l) {
            // q=0: gate on bit7 -> register pairs (r, r^2)
            {
                const float* U = &s_U[(l * NQ + 0) * 8];
                #pragma unroll
                for (int b6 = 0; b6 < 2; ++b6) {
                    const float i0r = xr[b6],      i0i = xi4[b6];
                    const float i1r = xr[2 + b6],  i1i = xi4[2 + b6];
                    xr[b6]      = U[0]*i0r - U[1]*i0i + U[2]*i1r - U[3]*i1i;
                    xi4[b6]     = U[0]*i0i + U[1]*i0r + U[2]*i1i + U[3]*i1r;
                    xr[2 + b6]  = U[4]*i0r - U[5]*i0i + U[6]*i1r - U[7]*i1i;
                    xi4[2 + b6] = U[4]*i0i + U[5]*i0r + U[6]*i1i + U[7]*i1r;
                }
            }
            // q=1: gate on bit6 -> register pairs (r, r^1)
            {
                const float* U = &s_U[(l * NQ + 1) * 8];
                #pragma unroll
                for (int b7 = 0; b7 < 2; ++b7) {
                    const int r0 = 2 * b7;
                    const float i0r = xr[r0],      i0i = xi4[r0];
                    const float i1r = xr[r0 + 1],  i1i = xi4[r0 + 1];
                    xr[r0]      = U[0]*i0r - U[1]*i0i + U[2]*i1r - U[3]*i1i;
                    xi4[r0]     = U[0]*i0i + U[1]*i0r + U[2]*i1i + U[3]*i1r;
                    xr[r0 + 1]  = U[4]*i0r - U[5]*i0i + U[6]*i1r - U[7]*i1i;
                    xi4[r0 + 1] = U[4]*i0i + U[5]*i0r + U[6]*i1i + U[7]*i1r;
                }
            }
            // q=2..7: lane-bit gates via shuffles, applied to all 4 regs
            #pragma unroll
            for (int q = 2; q < NQ; ++q) {
                const float* U = &s_U[(l * NQ + q) * 8];
                const int bp = 7 - q;
                const int bit = (lane >> bp) & 1;
                const float csr = bit ? U[6] : U[0];
                const float csi = bit ? U[7] : U[1];
                const float cpr = bit ? U[4] : U[2];
                const float cpi = bit ? U[5] : U[3];
                #pragma unroll
                for (int r = 0; r < 4; ++r) {
                    const float pr_ = __shfl_xor(xr[r],  1 << bp, 64);
                    const float pi_ = __shfl_xor(xi4[r], 1 << bp, 64);
                    const float nr = csr * xr[r]  - csi * xi4[r] + cpr * pr_ - cpi * pi_;
                    const float ni = csr * xi4[r] + csi * xr[r]  + cpr * pi_ + cpi * pr_;
                    xr[r] = nr; xi4[r] = ni;
                }
            }
            // CNOT-ring permutation via intra-wave LDS scratch (no barrier):
            // target amp 64r+lane sources permsrc(64r+lane) = sPl ^ {0,P40,P80,PC0}[r]
            #pragma unroll
            for (int r = 0; r < 4; ++r) {
                areb[64 * r + lane] = xr[r];
                aimb[64 * r + lane] = xi4[r];
            }
            const int s0 = sPl, s1 = sPl ^ P40, s2 = sPl ^ P80, s3 = sPl ^ PC0;
            xr[0] = areb[s0]; xi4[0] = aimb[s0];
            xr[1] = areb[s1]; xi4[1] = aimb[s1];
            xr[2] = areb[s2]; xi4[2] = aimb[s2];
            xr[3] = areb[s3]; xi4[3] = aimb[s3];
        }

        // Walsh-Hadamard Z expectations: bits 6,7 = register sign-combines,
        // bits 0..5 = 6-stage lane butterfly (R10-verified mapping).
        const float pr0 = xr[0]*xr[0] + xi4[0]*xi4[0];
        const float pr1 = xr[1]*xr[1] + xi4[1]*xi4[1];
        const float pr2 = xr[2]*xr[2] + xi4[2]*xi4[2];
        const float pr3 = xr[3]*xr[3] + xi4[3]*xi4[3];
        float t  = pr0 + pr1 + pr2 + pr3;
        float u6 = pr0 - pr1 + pr2 - pr3;   // sign = bit6 = r&1
        float u7 = pr0 + pr1 - pr2 - pr3;   // sign = bit7 = r>>1
        #pragma unroll
        for (int d = 0; d < 6; ++d) {
            const float p = __shfl_xor(t, 1 << d, 64);
            t = ((lane >> d) & 1) ? (p - t) : (t + p);
            u6 += __shfl_xor(u6, 1 << d, 64);
            u7 += __shfl_xor(u7, 1 << d, 64);
        }
        if (lane == 0) { s_q[0] = u7; s_q[1] = u6; }
        else if ((lane & (lane - 1)) == 0) {
            const int bp = 31 - __clz(lane);          // lane = 1<<bp
            s_q[7 - bp] = t;                          // <Z_q> with q = 7-bp
        }
        // head layer 1 (lanes 0..31; s_q read-after-write, same wave)
        float h = 0.0f;
        if (lane < 32) {
            float acc = head_b1[lane];
            #pragma unroll
            for (int k = 0; k < 8; ++k) acc += head_w1[lane * 14 + k] * s_q[k];
            #pragma unroll
            for (int k = 0; k < 6; ++k) acc += head_w1[lane * 14 + 8 + k] * scalars[b * 6 + k];
            h = fmaxf(acc * (head_bn_g[lane] * BN_RSQ) + head_bn_b[lane], 0.0f);
        }
        // head layer 2: 3 dot-products over 32 h values via butterfly reduce
        float p0 = (lane < 32) ? h * head_w2[lane]      : 0.0f;
        float p1 = (lane < 32) ? h * head_w2[32 + lane] : 0.0f;
        float p2 = (lane < 32) ? h * head_w2[64 + lane] : 0.0f;
        #pragma unroll
        for (int d = 0; d < 6; ++d) {
            p0 += __shfl_xor(p0, 1 << d, 64);
            p1 += __shfl_xor(p1, 1 << d, 64);
            p2 += __shfl_xor(p2, 1 << d, 64);
        }
        if (lane < 3) {
            const float v = (lane == 0) ? p0 : ((lane == 1) ? p1 : p2);
            out[b * 3 + lane] = v + head_b2[lane];
        }
    }
}

extern "C" void kernel_launch(void* const* d_in, const int* in_sizes, int n_in,
                              void* d_out, int out_size, void* d_ws, size_t ws_size,
                              hipStream_t stream) {
    const float* flux      = (const float*)d_in[0];
    const float* scalars   = (const float*)d_in[1];
    const float* conv1_w   = (const float*)d_in[2];
    const float* bn1_g     = (const float*)d_in[3];
    const float* bn1_b     = (const float*)d_in[4];
    const float* conv2_w   = (const float*)d_in[5];
    const float* bn2_g     = (const float*)d_in[6];
    const float* bn2_b     = (const float*)d_in[7];
    const float* proj_w1   = (const float*)d_in[8];
    const float* proj_b1   = (const float*)d_in[9];
    const float* proj_w2   = (const float*)d_in[10];
    const float* proj_b2   = (const float*)d_in[11];
    const float* q_weights = (const float*)d_in[12];
    const float* head_w1   = (const float*)d_in[13];
    const float* head_b1   = (const float*)d_in[14];
    const float* head_bn_g = (const float*)d_in[15];
    const float* head_bn_b = (const float*)d_in[16];
    const float* head_w2   = (const float*)d_in[17];
    const float* head_b2   = (const float*)d_in[18];

    const int B = in_sizes[0] / L0;   // 4096

    aec_fused_kernel<<<dim3(B), dim3(256), 0, stream>>>(
        flux, scalars, conv1_w, bn1_g, bn1_b, conv2_w, bn2_g, bn2_b,
        proj_w1, proj_b1, proj_w2, proj_b2, q_weights,
        head_w1, head_b1, head_bn_g, head_bn_b, head_w2, head_b2,
        (float*)d_out);
}

// Round 4
// 217.277 us; speedup vs baseline: 1.0082x; 1.0082x over previous
//
#include <hip/hip_runtime.h>
#include <math.h>

// Problem constants (fixed by reference setup_inputs)
#define L0   4448   // flux length
#define L1P  278    // after conv1(stride4,pad7)->1112 then maxpool4
#define L2   139    // after conv2(stride2,pad3) on 278
#define NQ   8
#define NL   3
#define SD   256

// LDS element/word map (float S[5620] = 22480 B)  [R14: Wb aliased into fxb]
//  fxb  bf16[4496]      el 0..4495      flux[x] at el x+8; el 0..7 & 4456..4495 zero
//  h1T  bf16[286][20]   el 4496..10215  row = pooled pos + 4; rows 0..3, 282..285 zero
//                       (rows 0..3 zero also serve as fxb overread pad, el<=4507)
//  Wc1  bf16[16][32]    el 10216..10727 conv1 weights (sign-flipped), K'=1..15 taps
//  featU f32[256]       words 5364..5619 (pool sums; s_U after proj1 — R4 invariant)
//  Wb   bf16[32][136]   el 0..4351      conv2 weights — written AFTER stage 1 into the
//                       dead fxb region (prefetched to regs in stage 0); read in stage 2.
// Aliases into dead fxb/Wb after stage2 (words 0..2247):
//  s_hidden w0..63, wp (Walsh parts, R15) w64..95, s_q w96..103,
//  ampc float2[256] (interleaved re,im) w256..767
#define H1T_EL 4496
#define WB_EL  0
#define WC1_EL 10216
#define FTW    5364

typedef __attribute__((ext_vector_type(4))) short short4v;
typedef __attribute__((ext_vector_type(8))) short short8;
typedef __attribute__((ext_vector_type(4))) float f32x4;
union FragU { short8 v; short4v h[2]; };

__device__ __forceinline__ short f2bf(float x) {   // fp32 -> bf16 (RNE)
    unsigned u = __float_as_uint(x);
    u += 0x7FFFu + ((u >> 16) & 1u);
    return (short)(u >> 16);
}

__device__ __forceinline__ short8 pack8(float4 a, float4 b) {
    short8 v;
    v[0] = f2bf(a.x); v[1] = f2bf(a.y); v[2] = f2bf(a.z); v[3] = f2bf(a.w);
    v[4] = f2bf(b.x); v[5] = f2bf(b.y); v[6] = f2bf(b.z); v[7] = f2bf(b.w);
    return v;
}

// CNOT-ring permutation (one layer of 8 CNOTs composed). Linear over GF(2).
constexpr int permsrc_c(int x) {
    for (int q = 7; q >= 0; --q) {
        int cb = 7 - q, tb = 7 - ((q + 1) & 7);
        x ^= ((x >> cb) & 1) << tb;
    }
    return x;
}
constexpr int P40 = permsrc_c(0x40);
constexpr int P80 = permsrc_c(0x80);
constexpr int PC0 = permsrc_c(0xC0);   // == P40 ^ P80 (GF(2)-linear)

__device__ __forceinline__ int permsrc(int x) {
    #pragma unroll
    for (int q = 7; q >= 0; --q) {
        int cb = 7 - q, tb = 7 - ((q + 1) & 7);
        x ^= ((x >> cb) & 1) << tb;
    }
    return x;
}

__global__ __launch_bounds__(256, 6)
void aec_fused_kernel(const float* __restrict__ flux,
                      const float* __restrict__ scalars,
                      const float* __restrict__ conv1_w,
                      const float* __restrict__ bn1_g, const float* __restrict__ bn1_b,
                      const float* __restrict__ conv2_w,
                      const float* __restrict__ bn2_g, const float* __restrict__ bn2_b,
                      const float* __restrict__ proj_w1, const float* __restrict__ proj_b1,
                      const float* __restrict__ proj_w2, const float* __restrict__ proj_b2,
                      const float* __restrict__ qw,
                      const float* __restrict__ head_w1, const float* __restrict__ head_b1,
                      const float* __restrict__ head_bn_g, const float* __restrict__ head_bn_b,
                      const float* __restrict__ head_w2, const float* __restrict__ head_b2,
                      float* __restrict__ out)
{
    const int b   = blockIdx.x;
    const int tid = threadIdx.x;

    __shared__ __align__(16) float S[5620];

    float* s_hidden = S;
    float* s_red    = S + 64;      // proj2 norm partials; later Walsh parts (wp)
    float* s_q      = S + 96;
    float* featU    = S + FTW;
    float* s_U      = S + FTW;     // gates overwrite featU AFTER proj1 (R4 invariant)

    const float BN_RSQ = 0.9999950000374997f;     // 1/sqrt(1+1e-5)

    // ---------------- stage 0: zeros + weight staging + flux staging ----------
    featU[tid] = 0.0f;
    if (tid < 4)                    S[tid] = 0.0f;          // fxb el 0..7
    else if (tid < 64)              S[2224 + tid] = 0.0f;   // fxb tail + h1T rows 0..3
    else if (tid < 104)             S[5004 + tid] = 0.0f;   // h1T rows 282..285
    {
        // Wc1[oc][k'] bf16: k'=0 zero, k'=1..15 = sgn*conv1_w[oc][k'-1], 16..31 zero.
        // Sign flip (exact) makes every effective bn1 scale >= 0 so maxpool can
        // run BEFORE the affine (monotone composition).
        const int oc = tid >> 4;
        const int q  = tid & 15;
        const float sgn = (bn1_g[oc] >= 0.0f) ? 1.0f : -1.0f;
        const int k0 = 2 * q, k1 = 2 * q + 1;
        const short e0 = (k0 >= 1 && k0 <= 15) ? f2bf(sgn * conv1_w[oc * 15 + k0 - 1]) : (short)0;
        const short e1 = (k1 <= 15)            ? f2bf(sgn * conv1_w[oc * 15 + k1 - 1]) : (short)0;
        const unsigned pk = (unsigned short)e0 | ((unsigned)(unsigned short)e1 << 16);
        *(unsigned*)((short*)S + WC1_EL + oc * 32 + 2 * q) = pk;
    }
    // Wb prefetch to REGISTERS only (Wb LDS region still holds live fxb data;
    // the ds_write happens after stage 1). Loads overlap flux HBM latency.
    short8 wbp0, wbp1;
    {
        const int oc = tid >> 3;
        const int k  = tid & 7;
        #pragma unroll
        for (int e = 0; e < 8; ++e) {
            wbp0[e] = (k < 7) ? f2bf(conv2_w[oc * 112 + e * 7 + k])       : (short)0;
            wbp1[e] = (k < 7) ? f2bf(conv2_w[oc * 112 + (8 + e) * 7 + k]) : (short)0;
        }
    }
    {
        // flux -> bf16 LDS (el x+8): 8 els per iteration, b128 stores.
        const float4* fg = (const float4*)(flux + (size_t)b * L0);
        short* fx = (short*)S;
        for (int t = tid; t < 556; t += 256) {
            float4 v0 = fg[2 * t], v1 = fg[2 * t + 1];
            *(short8*)(fx + 8 + 8 * t) = pack8(v0, v1);
        }
    }
    __syncthreads();

    // ---------------- stage 1: conv1 as MFMA (transposed D) + pool + bn --------
    // (R9-verified) D[j][oc] = X^T[16 j][32 k'] x Wc1^T[32][16 oc].
    {
        const int lane = tid & 63;
        const int wid  = tid >> 6;
        const int col  = lane & 15;
        const int quad = lane >> 4;
        const short* fx = (const short*)S;
        const short8 wfrag = *(const short8*)((const short*)S + WC1_EL + col * 32 + quad * 8);
        const float gsc = fabsf(bn1_g[col]) * BN_RSQ;
        const float gbt = bn1_b[col];

        for (int nt = wid; nt < 70; nt += 4) {
            const int jl = nt * 16 + col;          // A's m-row = conv position
            FragU xu;
            xu.h[0] = *(const short4v*)(fx + 4 * jl + quad * 8);
            xu.h[1] = *(const short4v*)(fx + 4 * jl + quad * 8 + 4);
            f32x4 acc = {0.f, 0.f, 0.f, 0.f};
            acc = __builtin_amdgcn_mfma_f32_16x16x32_bf16(xu.v, wfrag, acc, 0, 0, 0);
            const float m = fmaxf(fmaxf(acc[0], acc[1]), fmaxf(acc[2], acc[3]));
            const int p = nt * 4 + quad;           // pooled position
            if (p < L1P) {
                *((short*)S + H1T_EL + (4 + p) * 20 + col) =
                    f2bf(fmaxf(m * gsc + gbt, 0.0f));
            }
        }
    }
    __syncthreads();   // h1T complete; fxb now dead

    // Wb[oc][K'=k*16+ic] bf16, row stride 136 (k==7 row zero) -> dead fxb region.
    {
        const int oc = tid >> 3;
        const int k  = tid & 7;
        short8* dst = (short8*)((char*)S + (WB_EL + oc * 136 + k * 16) * 2);
        dst[0] = wbp0; dst[1] = wbp1;
    }
    __syncthreads();   // Wb ready; featU still pure pool sums

    // ---------------- stage 2: conv2 as MFMA (transposed D) + bn/relu + pool ----
    // (R9/R12-verified) D[j][oc] = X^T[144 j][128] x Wb^T[128][32 oc];
    // weight fragments hoisted (nt-invariant).
    {
        const int lane = tid & 63;
        const int wid  = tid >> 6;
        const int col  = lane & 15;
        const int quad = lane >> 4;
        const short* h1s = (const short*)S + H1T_EL;
        const char*  wbc = (const char*)((const short*)S + WB_EL);
        const float sc0 = bn2_g[col] * BN_RSQ,      bt0 = bn2_b[col];
        const float sc1 = bn2_g[col + 16] * BN_RSQ, bt1 = bn2_b[col + 16];

        short8 wa0[4], wa1[4];
        #pragma unroll
        for (int kb = 0; kb < 4; ++kb) {
            wa0[kb] = *(const short8*)(wbc + (col * 136        + kb*32 + quad*8) * 2);
            wa1[kb] = *(const short8*)(wbc + ((16 + col) * 136 + kb*32 + quad*8) * 2);
        }

        for (int nt = wid; nt < 9; nt += 4) {
            const int n0 = nt * 16;
            f32x4 acc0 = {0.f,0.f,0.f,0.f}, acc1 = {0.f,0.f,0.f,0.f};
            #pragma unroll
            for (int kb = 0; kb < 4; ++kb) {
                const int k   = 2 * kb + (quad >> 1);
                const int ic0 = (quad & 1) * 8;
                const int row = 2 * (n0 + col) + 1 + k;
                FragU bu;
                bu.h[0] = *(const short4v*)(h1s + row * 20 + ic0);
                bu.h[1] = *(const short4v*)(h1s + row * 20 + ic0 + 4);
                acc0 = __builtin_amdgcn_mfma_f32_16x16x32_bf16(bu.v, wa0[kb], acc0, 0, 0, 0);
                acc1 = __builtin_amdgcn_mfma_f32_16x16x32_bf16(bu.v, wa1[kb], acc1, 0, 0, 0);
            }
            const int   bA  = (8 * n0) / 139;
            const int   sB  = (139 * (bA + 1)) >> 3;      // j<=sB -> bA; j>=sB -> bA+1
            const float rcA = (bA == 2 || bA == 5) ? (1.0f/19.0f) : (1.0f/18.0f);
            const float rcB = (bA == 1 || bA == 4) ? (1.0f/19.0f) : (1.0f/18.0f);
            float va0 = 0.f, vb0 = 0.f, va1 = 0.f, vb1 = 0.f;
            #pragma unroll
            for (int r = 0; r < 4; ++r) {
                const int j = n0 + quad * 4 + r;
                float v0 = fmaxf(acc0[r] * sc0 + bt0, 0.0f);
                float v1 = fmaxf(acc1[r] * sc1 + bt1, 0.0f);
                if (j > 138) { v0 = 0.0f; v1 = 0.0f; }
                if (j <= sB) { va0 += v0; va1 += v1; }
                if (j >= sB) { vb0 += v0; vb1 += v1; }
            }
            va0 += __shfl_xor(va0, 16, 64); va0 += __shfl_xor(va0, 32, 64);
            va1 += __shfl_xor(va1, 16, 64); va1 += __shfl_xor(va1, 32, 64);
            vb0 += __shfl_xor(vb0, 16, 64); vb0 += __shfl_xor(vb0, 32, 64);
            vb1 += __shfl_xor(vb1, 16, 64); vb1 += __shfl_xor(vb1, 32, 64);
            if (quad == 0) {
                atomicAdd(&featU[col * 8 + bA],        va0 * rcA);
                atomicAdd(&featU[(col + 16) * 8 + bA], va1 * rcA);
                if (bA < 7) {
                    atomicAdd(&featU[col * 8 + bA + 1],        vb0 * rcB);
                    atomicAdd(&featU[(col + 16) * 8 + bA + 1], vb1 * rcB);
                }
            }
        }
    }
    __syncthreads();

    // ---------------- proj1 (256 -> 64), relu ----------------
    {
        const int o = tid >> 2, s = tid & 3;
        const float4* wg = (const float4*)(proj_w1 + 64 * tid);   // == o*256 + s*64
        const float4* xf = (const float4*)(featU + 64 * s);
        float acc = 0.0f;
        #pragma unroll
        for (int t = 0; t < 16; ++t) {
            float4 w4 = wg[t], x4 = xf[t];
            acc += w4.x * x4.x + w4.y * x4.y + w4.z * x4.z + w4.w * x4.w;
        }
        acc += __shfl_down(acc, 2, 64);
        acc += __shfl_down(acc, 1, 64);
        if (s == 0) s_hidden[o] = fmaxf(acc + proj_b1[o], 0.0f);
    }
    __syncthreads();

    // gate matrices into featU (feat consumed — only safe place, R4 invariant);
    // published by the __syncthreads() inside the normalize sequence below.
    if (tid < NL * NQ) {
        float phi = qw[tid * 3 + 0], th = qw[tid * 3 + 1], om = qw[tid * 3 + 2];
        float ch = cosf(0.5f * th), sh = sinf(0.5f * th);
        float a  = 0.5f * (phi + om), bb = 0.5f * (phi - om);
        float ca = cosf(a), sa = sinf(a), cb = cosf(bb), sb = sinf(bb);
        float* U = &s_U[tid * 8];
        U[0] =  ca * ch; U[1] = -sa * ch;   // U00
        U[2] = -cb * sh; U[3] = -sb * sh;   // U01
        U[4] =  cb * sh; U[5] = -sb * sh;   // U10
        U[6] =  ca * ch; U[7] =  sa * ch;   // U11
    }

    // ---------------- proj2 (64 -> 256) + L2 normalize ----------------
    float re;
    {
        const float4* wg = (const float4*)(proj_w2 + 64 * tid);
        const float4* hf = (const float4*)s_hidden;
        float acc = proj_b2[tid];
        #pragma unroll
        for (int t = 0; t < 16; ++t) {
            float4 w4 = wg[t], x4 = hf[t];
            acc += w4.x * x4.x + w4.y * x4.y + w4.z * x4.z + w4.w * x4.w;
        }
        float ss = acc * acc;
        #pragma unroll
        for (int off = 32; off >= 1; off >>= 1) ss += __shfl_xor(ss, off, 64);
        if ((tid & 63) == 0) s_red[tid >> 6] = ss;
        __syncthreads();                           // also publishes s_U
        float sst = s_red[0] + s_red[1] + s_red[2] + s_red[3];
        float n   = sqrtf(sst);
        float inv = 1.0f / fmaxf(n, 1e-12f);
        float xi  = acc * inv;
        if (n * inv < 1e-8f) xi = 0.0625f;        // uniform 1/sqrt(256)
        re = xi;                                   // initial state is real (im = 0)
    }

    // ---------------- R15: 4-wave tail — 1 amp/lane (amp index = tid) ---------
    // Amp bits 5..0 = lane bits -> q=2..7 are shfl_xor gates (verified math).
    // Amp bits 6,7 = wave bits  -> q=0,q=1 are one LDS exchange per layer.
    // CNOT-ring perm folded into next layer's read indices (GF(2) linearity):
    // permsrc(lane + 64 j) = permsrc(lane) ^ permsrc(j<<6), permsrc(j<<6) in
    // {0, P40, P80, PC0}. Walsh: per-wave signed butterfly + cross-wave combine.
    float2* ampc = (float2*)(S + 256);   // interleaved (re, im), words 256..767
    float*  wp   = S + 64;               // Walsh parts [4][7], words 64..91

    const int lane = tid & 63;
    const int w    = tid >> 6;
    const int b7   = w >> 1, b6 = w & 1;
    const int sl   = permsrc(lane);                      // may set bits 6,7
    const int pw   = (b6 ? P40 : 0) ^ (b7 ? P80 : 0);    // permsrc(w<<6)

    ampc[tid] = make_float2(re, 0.0f);
    __syncthreads();           // amps + s_U visible to all waves

    float ar = 0.0f, ai = 0.0f;
    #pragma unroll
    for (int l = 0; l < NL; ++l) {
        // --- exchange + combined q=0 (bit7), q=1 (bit6) gates ---
        float o_r[4], o_i[4];
        #pragma unroll
        for (int j = 0; j < 4; ++j) {
            const int src = (l == 0) ? (lane + 64 * j)
                                     : (sl ^ ((j & 1 ? P40 : 0) ^ (j & 2 ? P80 : 0)));
            const float2 v = ampc[src];
            o_r[j] = v.x;
            o_i[j] = (l == 0) ? 0.0f : v.y;
        }
        {
            const float* U0 = &s_U[(l * NQ + 0) * 8];
            const float* U1 = &s_U[(l * NQ + 1) * 8];
            // q0 row b7: tmp[b6'] = U0[b7][0]*old[0,b6'] + U0[b7][1]*old[1,b6']
            const float a0r = b7 ? U0[4] : U0[0], a0i = b7 ? U0[5] : U0[1];
            const float a1r = b7 ? U0[6] : U0[2], a1i = b7 ? U0[7] : U0[3];
            const float t0r = a0r*o_r[0] - a0i*o_i[0] + a1r*o_r[2] - a1i*o_i[2];
            const float t0i = a0r*o_i[0] + a0i*o_r[0] + a1r*o_i[2] + a1i*o_r[2];
            const float t1r = a0r*o_r[1] - a0i*o_i[1] + a1r*o_r[3] - a1i*o_i[3];
            const float t1i = a0r*o_i[1] + a0i*o_r[1] + a1r*o_i[3] + a1i*o_r[3];
            // q1 row b6: own = U1[b6][0]*tmp0 + U1[b6][1]*tmp1
            const float c0r = b6 ? U1[4] : U1[0], c0i = b6 ? U1[5] : U1[1];
            const float c1r = b6 ? U1[6] : U1[2], c1i = b6 ? U1[7] : U1[3];
            ar = c0r*t0r - c0i*t0i + c1r*t1r - c1i*t1i;
            ai = c0r*t0i + c0i*t0r + c1r*t1i + c1i*t1r;
        }
        // --- q=2..7: lane-bit gates via shuffles (R13-verified math, 1 reg) ---
        #pragma unroll
        for (int q = 2; q < NQ; ++q) {
            const float* U = &s_U[(l * NQ + q) * 8];
            const int bp  = 7 - q;
            const int bit = (lane >> bp) & 1;
            const float csr = bit ? U[6] : U[0];
            const float csi = bit ? U[7] : U[1];
            const float cpr = bit ? U[4] : U[2];
            const float cpi = bit ? U[5] : U[3];
            const float pr_ = __shfl_xor(ar, 1 << bp, 64);
            const float pi_ = __shfl_xor(ai, 1 << bp, 64);
            const float nr = csr * ar - csi * ai + cpr * pr_ - cpi * pi_;
            const float ni = csr * ai + csi * ar + cpr * pi_ + cpi * pr_;
            ar = nr; ai = ni;
        }
        __syncthreads();                 // all reads of ampc done before overwrite
        ampc[tid] = make_float2(ar, ai);
        __syncthreads();                 // writes visible for next read
    }

    // final CNOT-ring of layer 3: read own permuted amp
    {
        const float2 v = ampc[sl ^ pw];
        ar = v.x; ai = v.y;
    }

    // Walsh-Hadamard Z expectations: per-wave signed butterfly over lane bits
    // (lane L holds sum_l (-1)^{<l,L>} p_l — R10-verified mapping), then
    // cross-wave combine (bits 6,7 from per-wave totals with wave-bit signs).
    {
        const float p = ar * ar + ai * ai;
        float t = p;
        #pragma unroll
        for (int d = 0; d < 6; ++d) {
            const float ps = __shfl_xor(t, 1 << d, 64);
            t = ((lane >> d) & 1) ? (ps - t) : (t + ps);
        }
        if (lane == 0) wp[w * 7] = t;                       // wave total (Σp)
        else if ((lane & (lane - 1)) == 0) {
            const int d = 31 - __clz(lane);                 // lane = 1<<d, d 0..5
            wp[w * 7 + 1 + d] = t;                          // qubit 7-d partial
        }
    }
    __syncthreads();           // wp visible; waves 1-3 exit after this

    if (tid < 64) {
        // combine Walsh parts -> s_q (same-wave LDS, program-ordered)
        if (lane < 8) {
            float v;
            if (lane == 0)      v = wp[0] + wp[7] - wp[14] - wp[21];   // bit7 sign
            else if (lane == 1) v = wp[0] - wp[7] + wp[14] - wp[21];   // bit6 sign
            else {
                const int d = 7 - lane;                                 // q=2..7
                v = wp[1 + d] + wp[8 + d] + wp[15 + d] + wp[22 + d];
            }
            s_q[lane] = v;
        }
        // head layer 1 (lanes 0..31; s_q read-after-write, same wave)
        float h = 0.0f;
        if (lane < 32) {
            float acc = head_b1[lane];
            #pragma unroll
            for (int k = 0; k < 8; ++k) acc += head_w1[lane * 14 + k] * s_q[k];
            #pragma unroll
            for (int k = 0; k < 6; ++k) acc += head_w1[lane * 14 + 8 + k] * scalars[b * 6 + k];
            h = fmaxf(acc * (head_bn_g[lane] * BN_RSQ) + head_bn_b[lane], 0.0f);
        }
        // head layer 2: 3 dot-products over 32 h values via butterfly reduce
        float p0 = (lane < 32) ? h * head_w2[lane]      : 0.0f;
        float p1 = (lane < 32) ? h * head_w2[32 + lane] : 0.0f;
        float p2 = (lane < 32) ? h * head_w2[64 + lane] : 0.0f;
        #pragma unroll
        for (int d = 0; d < 6; ++d) {
            p0 += __shfl_xor(p0, 1 << d, 64);
            p1 += __shfl_xor(p1, 1 << d, 64);
            p2 += __shfl_xor(p2, 1 << d, 64);
        }
        if (lane < 3) {
            const float v = (lane == 0) ? p0 : ((lane == 1) ? p1 : p2);
            out[b * 3 + lane] = v + head_b2[lane];
        }
    }
}

extern "C" void kernel_launch(void* const* d_in, const int* in_sizes, int n_in,
                              void* d_out, int out_size, void* d_ws, size_t ws_size,
                              hipStream_t stream) {
    const float* flux      = (const float*)d_in[0];
    const float* scalars   = (const float*)d_in[1];
    const float* conv1_w   = (const float*)d_in[2];
    const float* bn1_g     = (const float*)d_in[3];
    const float* bn1_b     = (const float*)d_in[4];
    const float* conv2_w   = (const float*)d_in[5];
    const float* bn2_g     = (const float*)d_in[6];
    const float* bn2_b     = (const float*)d_in[7];
    const float* proj_w1   = (const float*)d_in[8];
    const float* proj_b1   = (const float*)d_in[9];
    const float* proj_w2   = (const float*)d_in[10];
    const float* proj_b2   = (const float*)d_in[11];
    const float* q_weights = (const float*)d_in[12];
    const float* head_w1   = (const float*)d_in[13];
    const float* head_b1   = (const float*)d_in[14];
    const float* head_bn_g = (const float*)d_in[15];
    const float* head_bn_b = (const float*)d_in[16];
    const float* head_w2   = (const float*)d_in[17];
    const float* head_b2   = (const float*)d_in[18];

    const int B = in_sizes[0] / L0;   // 4096

    aec_fused_kernel<<<dim3(B), dim3(256), 0, stream>>>(
        flux, scalars, conv1_w, bn1_g, bn1_b, conv2_w, bn2_g, bn2_b,
        proj_w1, proj_b1, proj_w2, proj_b2, q_weights,
        head_w1, head_b1, head_bn_g, head_bn_b, head_w2, head_b2,
        (float*)d_out);
}

// Round 7
// 201.502 us; speedup vs baseline: 1.0871x; 1.0783x over previous
//
#include <hip/hip_runtime.h>
#include <math.h>

// Problem constants (fixed by reference setup_inputs)
#define L0   4448   // flux length
#define L1P  278    // after conv1(stride4,pad7)->1112 then maxpool4
#define L2   139    // after conv2(stride2,pad3) on 278
#define NQ   8
#define NL   3
#define SD   256

// R16: TWO samples per block (iA=2b, iB=2b+1), mirrored LDS regions SA/SB of
// 5620 words each (same internal map as R14/R15). All weights shared:
// Wc1, Wb live in SA only; s_U (gates) in SA only; proj/head weights loaded
// once per thread and dotted against both samples (ILP x2, weight traffic /2).
//
// Per-region element/word map (words rel. to region base):
//  fxb  bf16[4496]      el 0..4495      flux at el x+8; el 0..7 & 4456..4575 zero
//  h1T  bf16[286][20]   el 4496..10215  rows 0..3 & 282..285 zero (also fxb pad)
//  Wc1  bf16[16][32]    el 10216..10727 (SA ONLY; SB region here is dead/garbage,
//                       read only by the masked stage-2 nt=8 overread)
//  featU f32[256]       words 5364..5619 (s_U alias in SA after proj1 — R4 inv.)
//  Wb   bf16[32][136]   el 0..4351 (SA ONLY) — written after stage 1 into dead fxb_A
// Post-stage-2 aliases in each region (fxb/Wb dead): s_hidden w0..63,
// s_red/wp w64..95, s_q w96..103, ampc float2[256] w256..767.
#define H1T_EL 4496
#define WB_EL  0
#define WC1_EL 10216
#define FTW    5364
#define RGN    5620

typedef __attribute__((ext_vector_type(4))) short short4v;
typedef __attribute__((ext_vector_type(8))) short short8;
typedef __attribute__((ext_vector_type(4))) float f32x4;
union FragU { short8 v; short4v h[2]; };

__device__ __forceinline__ short f2bf(float x) {   // fp32 -> bf16 (RNE)
    unsigned u = __float_as_uint(x);
    u += 0x7FFFu + ((u >> 16) & 1u);
    return (short)(u >> 16);
}

__device__ __forceinline__ short8 pack8(float4 a, float4 b) {
    short8 v;
    v[0] = f2bf(a.x); v[1] = f2bf(a.y); v[2] = f2bf(a.z); v[3] = f2bf(a.w);
    v[4] = f2bf(b.x); v[5] = f2bf(b.y); v[6] = f2bf(b.z); v[7] = f2bf(b.w);
    return v;
}

// CNOT-ring permutation (one layer of 8 CNOTs composed). Linear over GF(2).
constexpr int permsrc_c(int x) {
    for (int q = 7; q >= 0; --q) {
        int cb = 7 - q, tb = 7 - ((q + 1) & 7);
        x ^= ((x >> cb) & 1) << tb;
    }
    return x;
}
constexpr int P40 = permsrc_c(0x40);
constexpr int P80 = permsrc_c(0x80);
constexpr int PC0 = permsrc_c(0xC0);   // == P40 ^ P80 (GF(2)-linear)

__device__ __forceinline__ int permsrc(int x) {
    #pragma unroll
    for (int q = 7; q >= 0; --q) {
        int cb = 7 - q, tb = 7 - ((q + 1) & 7);
        x ^= ((x >> cb) & 1) << tb;
    }
    return x;
}

__global__ __launch_bounds__(256, 3)
void aec_fused_kernel(const float* __restrict__ flux,
                      const float* __restrict__ scalars,
                      const float* __restrict__ conv1_w,
                      const float* __restrict__ bn1_g, const float* __restrict__ bn1_b,
                      const float* __restrict__ conv2_w,
                      const float* __restrict__ bn2_g, const float* __restrict__ bn2_b,
                      const float* __restrict__ proj_w1, const float* __restrict__ proj_b1,
                      const float* __restrict__ proj_w2, const float* __restrict__ proj_b2,
                      const float* __restrict__ qw,
                      const float* __restrict__ head_w1, const float* __restrict__ head_b1,
                      const float* __restrict__ head_bn_g, const float* __restrict__ head_bn_b,
                      const float* __restrict__ head_w2, const float* __restrict__ head_b2,
                      float* __restrict__ out)
{
    const int iA  = 2 * blockIdx.x;
    const int iB  = iA + 1;
    const int tid = threadIdx.x;

    __shared__ __align__(16) float S2[2 * RGN];
    float* SA = S2;
    float* SB = S2 + RGN;

    float* s_hiddenA = SA;           float* s_hiddenB = SB;
    float* s_redA    = SA + 64;      float* s_redB    = SB + 64;   // later wp
    float* s_qA      = SA + 96;      float* s_qB      = SB + 96;
    float* featUA    = SA + FTW;     float* featUB    = SB + FTW;
    float* s_U       = SA + FTW;     // gates overwrite featUA AFTER proj1 (R4 inv.)

    const float BN_RSQ = 0.9999950000374997f;     // 1/sqrt(1+1e-5)

    // ---------------- stage 0: zeros + weight staging + flux staging ----------
    featUA[tid] = 0.0f;
    featUB[tid] = 0.0f;
    if (tid < 4)       { SA[tid] = 0.0f;        SB[tid] = 0.0f; }
    else if (tid < 64) { SA[2224 + tid] = 0.0f; SB[2224 + tid] = 0.0f; }
    else if (tid < 104){ SA[5004 + tid] = 0.0f; SB[5004 + tid] = 0.0f; }
    {
        // Wc1 (SHARED, SA only): k'=0 zero, k'=1..15 = sgn*conv1_w, 16..31 zero.
        const int oc = tid >> 4;
        const int q  = tid & 15;
        const float sgn = (bn1_g[oc] >= 0.0f) ? 1.0f : -1.0f;
        const int k0 = 2 * q, k1 = 2 * q + 1;
        const short e0 = (k0 >= 1 && k0 <= 15) ? f2bf(sgn * conv1_w[oc * 15 + k0 - 1]) : (short)0;
        const short e1 = (k1 <= 15)            ? f2bf(sgn * conv1_w[oc * 15 + k1 - 1]) : (short)0;
        const unsigned pk = (unsigned short)e0 | ((unsigned)(unsigned short)e1 << 16);
        *(unsigned*)((short*)SA + WC1_EL + oc * 32 + 2 * q) = pk;
    }
    // Wb prefetch to REGISTERS (SHARED; ds_write into dead fxb_A after stage 1).
    short8 wbp0, wbp1;
    {
        const int oc = tid >> 3;
        const int k  = tid & 7;
        #pragma unroll
        for (int e = 0; e < 8; ++e) {
            wbp0[e] = (k < 7) ? f2bf(conv2_w[oc * 112 + e * 7 + k])       : (short)0;
            wbp1[e] = (k < 7) ? f2bf(conv2_w[oc * 112 + (8 + e) * 7 + k]) : (short)0;
        }
    }
    {
        // flux -> bf16 LDS for BOTH samples (interleaved loads: 2x outstanding).
        const float4* fgA = (const float4*)(flux + (size_t)iA * L0);
        const float4* fgB = (const float4*)(flux + (size_t)iB * L0);
        short* fxA = (short*)SA;
        short* fxB = (short*)SB;
        for (int t = tid; t < 556; t += 256) {
            float4 a0 = fgA[2 * t], a1 = fgA[2 * t + 1];
            float4 b0 = fgB[2 * t], b1 = fgB[2 * t + 1];
            *(short8*)(fxA + 8 + 8 * t) = pack8(a0, a1);
            *(short8*)(fxB + 8 + 8 * t) = pack8(b0, b1);
        }
    }
    __syncthreads();

    // ---------------- stage 1: conv1 as MFMA (transposed D) + pool + bn --------
    // (R9-verified) D[j][oc] = X^T[16 j][32 k'] x Wc1^T[32][16 oc]. A/B interleaved.
    {
        const int lane = tid & 63;
        const int wid  = tid >> 6;
        const int col  = lane & 15;
        const int quad = lane >> 4;
        const short* fxA = (const short*)SA;
        const short* fxB = (const short*)SB;
        const short8 wfrag = *(const short8*)((const short*)SA + WC1_EL + col * 32 + quad * 8);
        const float gsc = fabsf(bn1_g[col]) * BN_RSQ;
        const float gbt = bn1_b[col];

        for (int nt = wid; nt < 70; nt += 4) {
            const int jl = nt * 16 + col;          // A's m-row = conv position
            FragU xuA, xuB;
            xuA.h[0] = *(const short4v*)(fxA + 4 * jl + quad * 8);
            xuA.h[1] = *(const short4v*)(fxA + 4 * jl + quad * 8 + 4);
            xuB.h[0] = *(const short4v*)(fxB + 4 * jl + quad * 8);
            xuB.h[1] = *(const short4v*)(fxB + 4 * jl + quad * 8 + 4);
            f32x4 accA = {0.f, 0.f, 0.f, 0.f};
            f32x4 accB = {0.f, 0.f, 0.f, 0.f};
            accA = __builtin_amdgcn_mfma_f32_16x16x32_bf16(xuA.v, wfrag, accA, 0, 0, 0);
            accB = __builtin_amdgcn_mfma_f32_16x16x32_bf16(xuB.v, wfrag, accB, 0, 0, 0);
            const float mA = fmaxf(fmaxf(accA[0], accA[1]), fmaxf(accA[2], accA[3]));
            const float mB = fmaxf(fmaxf(accB[0], accB[1]), fmaxf(accB[2], accB[3]));
            const int p = nt * 4 + quad;           // pooled position
            if (p < L1P) {
                *((short*)SA + H1T_EL + (4 + p) * 20 + col) =
                    f2bf(fmaxf(mA * gsc + gbt, 0.0f));
                *((short*)SB + H1T_EL + (4 + p) * 20 + col) =
                    f2bf(fmaxf(mB * gsc + gbt, 0.0f));
            }
        }
    }
    __syncthreads();   // h1T_A/B complete; fxb_A/B now dead

    // Wb[oc][K'=k*16+ic] bf16, row stride 136 (k==7 row zero) -> dead fxb_A.
    {
        const int oc = tid >> 3;
        const int k  = tid & 7;
        short8* dst = (short8*)((char*)SA + (WB_EL + oc * 136 + k * 16) * 2);
        dst[0] = wbp0; dst[1] = wbp1;
    }
    __syncthreads();   // Wb ready; featU_A/B still pure pool sums

    // ---------------- stage 2: conv2 as MFMA + bn/relu + pool (A/B interleaved) -
    // (R9/R12-verified) D[j][oc] = X^T[144 j][128] x Wb^T[128][32 oc].
    {
        const int lane = tid & 63;
        const int wid  = tid >> 6;
        const int col  = lane & 15;
        const int quad = lane >> 4;
        const short* h1sA = (const short*)SA + H1T_EL;
        const short* h1sB = (const short*)SB + H1T_EL;
        const char*  wbc  = (const char*)((const short*)SA + WB_EL);
        const float sc0 = bn2_g[col] * BN_RSQ,      bt0 = bn2_b[col];
        const float sc1 = bn2_g[col + 16] * BN_RSQ, bt1 = bn2_b[col + 16];

        short8 wa0[4], wa1[4];
        #pragma unroll
        for (int kb = 0; kb < 4; ++kb) {
            wa0[kb] = *(const short8*)(wbc + (col * 136        + kb*32 + quad*8) * 2);
            wa1[kb] = *(const short8*)(wbc + ((16 + col) * 136 + kb*32 + quad*8) * 2);
        }

        for (int nt = wid; nt < 9; nt += 4) {
            const int n0 = nt * 16;
            f32x4 accA0 = {0.f,0.f,0.f,0.f}, accA1 = {0.f,0.f,0.f,0.f};
            f32x4 accB0 = {0.f,0.f,0.f,0.f}, accB1 = {0.f,0.f,0.f,0.f};
            #pragma unroll
            for (int kb = 0; kb < 4; ++kb) {
                const int k   = 2 * kb + (quad >> 1);
                const int ic0 = (quad & 1) * 8;
                const int row = 2 * (n0 + col) + 1 + k;
                FragU buA, buB;
                buA.h[0] = *(const short4v*)(h1sA + row * 20 + ic0);
                buA.h[1] = *(const short4v*)(h1sA + row * 20 + ic0 + 4);
                buB.h[0] = *(const short4v*)(h1sB + row * 20 + ic0);
                buB.h[1] = *(const short4v*)(h1sB + row * 20 + ic0 + 4);
                accA0 = __builtin_amdgcn_mfma_f32_16x16x32_bf16(buA.v, wa0[kb], accA0, 0, 0, 0);
                accA1 = __builtin_amdgcn_mfma_f32_16x16x32_bf16(buA.v, wa1[kb], accA1, 0, 0, 0);
                accB0 = __builtin_amdgcn_mfma_f32_16x16x32_bf16(buB.v, wa0[kb], accB0, 0, 0, 0);
                accB1 = __builtin_amdgcn_mfma_f32_16x16x32_bf16(buB.v, wa1[kb], accB1, 0, 0, 0);
            }
            const int   bk  = (8 * n0) / 139;
            const int   sBd = (139 * (bk + 1)) >> 3;      // j<=sBd -> bk; j>=sBd -> bk+1
            const float rc0 = (bk == 2 || bk == 5) ? (1.0f/19.0f) : (1.0f/18.0f);
            const float rc1 = (bk == 1 || bk == 4) ? (1.0f/19.0f) : (1.0f/18.0f);
            float vaA0 = 0.f, vbA0 = 0.f, vaA1 = 0.f, vbA1 = 0.f;
            float vaB0 = 0.f, vbB0 = 0.f, vaB1 = 0.f, vbB1 = 0.f;
            #pragma unroll
            for (int r = 0; r < 4; ++r) {
                const int j = n0 + quad * 4 + r;
                float vA0 = fmaxf(accA0[r] * sc0 + bt0, 0.0f);
                float vA1 = fmaxf(accA1[r] * sc1 + bt1, 0.0f);
                float vB0 = fmaxf(accB0[r] * sc0 + bt0, 0.0f);
                float vB1 = fmaxf(accB1[r] * sc1 + bt1, 0.0f);
                if (j > 138) { vA0 = 0.0f; vA1 = 0.0f; vB0 = 0.0f; vB1 = 0.0f; }
                if (j <= sBd) { vaA0 += vA0; vaA1 += vA1; vaB0 += vB0; vaB1 += vB1; }
                if (j >= sBd) { vbA0 += vA0; vbA1 += vA1; vbB0 += vB0; vbB1 += vB1; }
            }
            vaA0 += __shfl_xor(vaA0, 16, 64); vaA0 += __shfl_xor(vaA0, 32, 64);
            vaA1 += __shfl_xor(vaA1, 16, 64); vaA1 += __shfl_xor(vaA1, 32, 64);
            vbA0 += __shfl_xor(vbA0, 16, 64); vbA0 += __shfl_xor(vbA0, 32, 64);
            vbA1 += __shfl_xor(vbA1, 16, 64); vbA1 += __shfl_xor(vbA1, 32, 64);
            vaB0 += __shfl_xor(vaB0, 16, 64); vaB0 += __shfl_xor(vaB0, 32, 64);
            vaB1 += __shfl_xor(vaB1, 16, 64); vaB1 += __shfl_xor(vaB1, 32, 64);
            vbB0 += __shfl_xor(vbB0, 16, 64); vbB0 += __shfl_xor(vbB0, 32, 64);
            vbB1 += __shfl_xor(vbB1, 16, 64); vbB1 += __shfl_xor(vbB1, 32, 64);
            if (quad == 0) {
                atomicAdd(&featUA[col * 8 + bk],        vaA0 * rc0);
                atomicAdd(&featUA[(col + 16) * 8 + bk], vaA1 * rc0);
                atomicAdd(&featUB[col * 8 + bk],        vaB0 * rc0);
                atomicAdd(&featUB[(col + 16) * 8 + bk], vaB1 * rc0);
                if (bk < 7) {
                    atomicAdd(&featUA[col * 8 + bk + 1],        vbA0 * rc1);
                    atomicAdd(&featUA[(col + 16) * 8 + bk + 1], vbA1 * rc1);
                    atomicAdd(&featUB[col * 8 + bk + 1],        vbB0 * rc1);
                    atomicAdd(&featUB[(col + 16) * 8 + bk + 1], vbB1 * rc1);
                }
            }
        }
    }
    __syncthreads();

    // ---------------- proj1 (256 -> 64), relu — shared weights, 2 dots --------
    {
        const int o = tid >> 2, s = tid & 3;
        const float4* wg  = (const float4*)(proj_w1 + 64 * tid);   // == o*256 + s*64
        const float4* xfA = (const float4*)(featUA + 64 * s);
        const float4* xfB = (const float4*)(featUB + 64 * s);
        float accA = 0.0f, accB = 0.0f;
        #pragma unroll
        for (int t = 0; t < 16; ++t) {
            float4 w4 = wg[t], a4 = xfA[t], b4 = xfB[t];
            accA += w4.x * a4.x + w4.y * a4.y + w4.z * a4.z + w4.w * a4.w;
            accB += w4.x * b4.x + w4.y * b4.y + w4.z * b4.z + w4.w * b4.w;
        }
        accA += __shfl_down(accA, 2, 64); accB += __shfl_down(accB, 2, 64);
        accA += __shfl_down(accA, 1, 64); accB += __shfl_down(accB, 1, 64);
        if (s == 0) {
            s_hiddenA[o] = fmaxf(accA + proj_b1[o], 0.0f);
            s_hiddenB[o] = fmaxf(accB + proj_b1[o], 0.0f);
        }
    }
    __syncthreads();

    // gate matrices into featUA alias (SHARED; published by norm barrier below)
    if (tid < NL * NQ) {
        float phi = qw[tid * 3 + 0], th = qw[tid * 3 + 1], om = qw[tid * 3 + 2];
        float ch = cosf(0.5f * th), sh = sinf(0.5f * th);
        float a  = 0.5f * (phi + om), bb = 0.5f * (phi - om);
        float ca = cosf(a), sa = sinf(a), cb = cosf(bb), sb = sinf(bb);
        float* U = &s_U[tid * 8];
        U[0] =  ca * ch; U[1] = -sa * ch;   // U00
        U[2] = -cb * sh; U[3] = -sb * sh;   // U01
        U[4] =  cb * sh; U[5] = -sb * sh;   // U10
        U[6] =  ca * ch; U[7] =  sa * ch;   // U11
    }

    // ---------------- proj2 (64 -> 256) + L2 normalize (A/B interleaved) ------
    float reA, reB;
    {
        const float4* wg  = (const float4*)(proj_w2 + 64 * tid);
        const float4* hfA = (const float4*)s_hiddenA;
        const float4* hfB = (const float4*)s_hiddenB;
        float accA = proj_b2[tid], accB = accA;
        #pragma unroll
        for (int t = 0; t < 16; ++t) {
            float4 w4 = wg[t], a4 = hfA[t], b4 = hfB[t];
            accA += w4.x * a4.x + w4.y * a4.y + w4.z * a4.z + w4.w * a4.w;
            accB += w4.x * b4.x + w4.y * b4.y + w4.z * b4.z + w4.w * b4.w;
        }
        float ssA = accA * accA, ssB = accB * accB;
        #pragma unroll
        for (int off = 32; off >= 1; off >>= 1) {
            ssA += __shfl_xor(ssA, off, 64);
            ssB += __shfl_xor(ssB, off, 64);
        }
        if ((tid & 63) == 0) { s_redA[tid >> 6] = ssA; s_redB[tid >> 6] = ssB; }
        __syncthreads();                           // also publishes s_U
        float sstA = s_redA[0] + s_redA[1] + s_redA[2] + s_redA[3];
        float sstB = s_redB[0] + s_redB[1] + s_redB[2] + s_redB[3];
        float nA = sqrtf(sstA), nB = sqrtf(sstB);
        float invA = 1.0f / fmaxf(nA, 1e-12f);
        float invB = 1.0f / fmaxf(nB, 1e-12f);
        float xiA = accA * invA, xiB = accB * invB;
        if (nA * invA < 1e-8f) xiA = 0.0625f;      // uniform 1/sqrt(256)
        if (nB * invB < 1e-8f) xiB = 0.0625f;
        reA = xiA; reB = xiB;                      // initial state real (im = 0)
    }

    // ---------------- R15/R16 tail: 4-wave circuit, A/B interleaved -----------
    // Amp bits 5..0 = lane bits -> q=2..7 shfl_xor gates; bits 6,7 = wave bits
    // -> q=0,q=1 one LDS exchange per layer; CNOT perm folded into reads
    // (GF(2) linearity). Gate coeffs shared between samples.
    float2* ampcA = (float2*)(SA + 256);
    float2* ampcB = (float2*)(SB + 256);
    float*  wpA   = SA + 64;             // Walsh parts [4][7]
    float*  wpB   = SB + 64;

    const int lane = tid & 63;
    const int w    = tid >> 6;
    const int b7   = w >> 1, b6 = w & 1;
    const int sl   = permsrc(lane);                      // may set bits 6,7
    const int pw   = (b6 ? P40 : 0) ^ (b7 ? P80 : 0);    // permsrc(w<<6)

    ampcA[tid] = make_float2(reA, 0.0f);
    ampcB[tid] = make_float2(reB, 0.0f);
    __syncthreads();           // amps + s_U visible to all waves

    float arA = 0.0f, aiA = 0.0f, arB = 0.0f, aiB = 0.0f;
    #pragma unroll
    for (int l = 0; l < NL; ++l) {
        // --- exchange + combined q=0 (bit7), q=1 (bit6) gates ---
        float oAr[4], oAi[4], oBr[4], oBi[4];
        #pragma unroll
        for (int j = 0; j < 4; ++j) {
            const int src = (l == 0) ? (lane + 64 * j)
                                     : (sl ^ ((j & 1 ? P40 : 0) ^ (j & 2 ? P80 : 0)));
            const float2 vA = ampcA[src];
            const float2 vB = ampcB[src];
            oAr[j] = vA.x; oAi[j] = (l == 0) ? 0.0f : vA.y;
            oBr[j] = vB.x; oBi[j] = (l == 0) ? 0.0f : vB.y;
        }
        {
            const float* U0 = &s_U[(l * NQ + 0) * 8];
            const float* U1 = &s_U[(l * NQ + 1) * 8];
            const float a0r = b7 ? U0[4] : U0[0], a0i = b7 ? U0[5] : U0[1];
            const float a1r = b7 ? U0[6] : U0[2], a1i = b7 ? U0[7] : U0[3];
            const float c0r = b6 ? U1[4] : U1[0], c0i = b6 ? U1[5] : U1[1];
            const float c1r = b6 ? U1[6] : U1[2], c1i = b6 ? U1[7] : U1[3];
            // A
            const float tA0r = a0r*oAr[0] - a0i*oAi[0] + a1r*oAr[2] - a1i*oAi[2];
            const float tA0i = a0r*oAi[0] + a0i*oAr[0] + a1r*oAi[2] + a1i*oAr[2];
            const float tA1r = a0r*oAr[1] - a0i*oAi[1] + a1r*oAr[3] - a1i*oAi[3];
            const float tA1i = a0r*oAi[1] + a0i*oAr[1] + a1r*oAi[3] + a1i*oAr[3];
            arA = c0r*tA0r - c0i*tA0i + c1r*tA1r - c1i*tA1i;
            aiA = c0r*tA0i + c0i*tA0r + c1r*tA1i + c1i*tA1r;
            // B
            const float tB0r = a0r*oBr[0] - a0i*oBi[0] + a1r*oBr[2] - a1i*oBi[2];
            const float tB0i = a0r*oBi[0] + a0i*oBr[0] + a1r*oBi[2] + a1i*oBr[2];
            const float tB1r = a0r*oBr[1] - a0i*oBi[1] + a1r*oBr[3] - a1i*oBi[3];
            const float tB1i = a0r*oBi[1] + a0i*oBr[1] + a1r*oBi[3] + a1i*oBr[3];
            arB = c0r*tB0r - c0i*tB0i + c1r*tB1r - c1i*tB1i;
            aiB = c0r*tB0i + c0i*tB0r + c1r*tB1i + c1i*tB1r;
        }
        // --- q=2..7: lane-bit gates via shuffles, A/B chains interleaved ---
        #pragma unroll
        for (int q = 2; q < NQ; ++q) {
            const float* U = &s_U[(l * NQ + q) * 8];
            const int bp  = 7 - q;
            const int bit = (lane >> bp) & 1;
            const float csr = bit ? U[6] : U[0];
            const float csi = bit ? U[7] : U[1];
            const float cpr = bit ? U[4] : U[2];
            const float cpi = bit ? U[5] : U[3];
            const float pAr = __shfl_xor(arA, 1 << bp, 64);
            const float pAi = __shfl_xor(aiA, 1 << bp, 64);
            const float pBr = __shfl_xor(arB, 1 << bp, 64);
            const float pBi = __shfl_xor(aiB, 1 << bp, 64);
            const float nAr = csr * arA - csi * aiA + cpr * pAr - cpi * pAi;
            const float nAi = csr * aiA + csi * arA + cpr * pAi + cpi * pAr;
            const float nBr = csr * arB - csi * aiB + cpr * pBr - cpi * pBi;
            const float nBi = csr * aiB + csi * arB + cpr * pBi + cpi * pBr;
            arA = nAr; aiA = nAi; arB = nBr; aiB = nBi;
        }
        __syncthreads();                 // all reads of ampc done before overwrite
        ampcA[tid] = make_float2(arA, aiA);
        ampcB[tid] = make_float2(arB, aiB);
        __syncthreads();                 // writes visible for next read
    }

    // final CNOT-ring of layer 3: read own permuted amp
    {
        const float2 vA = ampcA[sl ^ pw];
        const float2 vB = ampcB[sl ^ pw];
        arA = vA.x; aiA = vA.y; arB = vB.x; aiB = vB.y;
    }

    // Walsh-Hadamard: per-wave signed butterfly (R10-verified), A/B interleaved
    {
        const float pA = arA * arA + aiA * aiA;
        const float pB = arB * arB + aiB * aiB;
        float tA = pA, tB = pB;
        #pragma unroll
        for (int d = 0; d < 6; ++d) {
            const float sAs = __shfl_xor(tA, 1 << d, 64);
            const float sBs = __shfl_xor(tB, 1 << d, 64);
            tA = ((lane >> d) & 1) ? (sAs - tA) : (tA + sAs);
            tB = ((lane >> d) & 1) ? (sBs - tB) : (tB + sBs);
        }
        if (lane == 0) { wpA[w * 7] = tA; wpB[w * 7] = tB; }
        else if ((lane & (lane - 1)) == 0) {
            const int d = 31 - __clz(lane);                 // lane = 1<<d, d 0..5
            wpA[w * 7 + 1 + d] = tA;                        // qubit 7-d partial
            wpB[w * 7 + 1 + d] = tB;
        }
    }
    __syncthreads();           // wp visible; waves 2-3 exit after this

    // wave 0 -> sample A, wave 1 -> sample B (independent heads in parallel)
    if (tid < 128) {
        const int sm = tid >> 6;
        const float* wpp = sm ? wpB : wpA;
        float* sq        = sm ? s_qB : s_qA;
        const int bb     = sm ? iB : iA;
        // combine Walsh parts -> s_q (same-wave LDS, program-ordered)
        if (lane < 8) {
            float v;
            if (lane == 0)      v = wpp[0] + wpp[7] - wpp[14] - wpp[21];   // bit7
            else if (lane == 1) v = wpp[0] - wpp[7] + wpp[14] - wpp[21];   // bit6
            else {
                const int d = 7 - lane;                                     // q=2..7
                v = wpp[1 + d] + wpp[8 + d] + wpp[15 + d] + wpp[22 + d];
            }
            sq[lane] = v;
        }
        // head layer 1 (lanes 0..31; sq read-after-write, same wave)
        float h = 0.0f;
        if (lane < 32) {
            float acc = head_b1[lane];
            #pragma unroll
            for (int k = 0; k < 8; ++k) acc += head_w1[lane * 14 + k] * sq[k];
            #pragma unroll
            for (int k = 0; k < 6; ++k) acc += head_w1[lane * 14 + 8 + k] * scalars[bb * 6 + k];
            h = fmaxf(acc * (head_bn_g[lane] * BN_RSQ) + head_bn_b[lane], 0.0f);
        }
        // head layer 2: 3 dot-products over 32 h values via butterfly reduce
        float p0 = (lane < 32) ? h * head_w2[lane]      : 0.0f;
        float p1 = (lane < 32) ? h * head_w2[32 + lane] : 0.0f;
        float p2 = (lane < 32) ? h * head_w2[64 + lane] : 0.0f;
        #pragma unroll
        for (int d = 0; d < 6; ++d) {
            p0 += __shfl_xor(p0, 1 << d, 64);
            p1 += __shfl_xor(p1, 1 << d, 64);
            p2 += __shfl_xor(p2, 1 << d, 64);
        }
        if (lane < 3) {
            const float v = (lane == 0) ? p0 : ((lane == 1) ? p1 : p2);
            out[bb * 3 + lane] = v + head_b2[lane];
        }
    }
}

extern "C" void kernel_launch(void* const* d_in, const int* in_sizes, int n_in,
                              void* d_out, int out_size, void* d_ws, size_t ws_size,
                              hipStream_t stream) {
    const float* flux      = (const float*)d_in[0];
    const float* scalars   = (const float*)d_in[1];
    const float* conv1_w   = (const float*)d_in[2];
    const float* bn1_g     = (const float*)d_in[3];
    const float* bn1_b     = (const float*)d_in[4];
    const float* conv2_w   = (const float*)d_in[5];
    const float* bn2_g     = (const float*)d_in[6];
    const float* bn2_b     = (const float*)d_in[7];
    const float* proj_w1   = (const float*)d_in[8];
    const float* proj_b1   = (const float*)d_in[9];
    const float* proj_w2   = (const float*)d_in[10];
    const float* proj_b2   = (const float*)d_in[11];
    const float* q_weights = (const float*)d_in[12];
    const float* head_w1   = (const float*)d_in[13];
    const float* head_b1   = (const float*)d_in[14];
    const float* head_bn_g = (const float*)d_in[15];
    const float* head_bn_b = (const float*)d_in[16];
    const float* head_w2   = (const float*)d_in[17];
    const float* head_b2   = (const float*)d_in[18];

    const int B = in_sizes[0] / L0;   // 4096

    aec_fused_kernel<<<dim3(B / 2), dim3(256), 0, stream>>>(
        flux, scalars, conv1_w, bn1_g, bn1_b, conv2_w, bn2_g, bn2_b,
        proj_w1, proj_b1, proj_w2, proj_b2, q_weights,
        head_w1, head_b1, head_bn_g, head_bn_b, head_w2, head_b2,
        (float*)d_out);
}